// Round 5
// baseline (56.335 us; speedup 1.0000x reference)
//
#include <hip/hip_runtime.h>
#include <hip/hip_bf16.h>
#include <stdint.h>

#define DIM 1024
#define NTOK 8192

#define BM 64
#define BN 64
#define BK 32

typedef __attribute__((ext_vector_type(8))) short bf16x8;
typedef __attribute__((ext_vector_type(4))) float f32x4;

__device__ __forceinline__ unsigned short f2bf(float f) {
    union { float f; uint32_t u; } v; v.f = f;
    uint32_t u = v.u;
    u += 0x7FFFu + ((u >> 16) & 1u);   // round-to-nearest-even
    return (unsigned short)(u >> 16);
}
__device__ __forceinline__ float bf2f(unsigned short h) {
    union { uint32_t u; float f; } v; v.u = ((uint32_t)h) << 16; return v.f;
}

// async global->LDS, 16B per lane (dest must be wave-base + lane*16, linear)
#define GLOAD_LDS16(g, l)                                                \
    __builtin_amdgcn_global_load_lds(                                    \
        (const __attribute__((address_space(1))) void*)(g),              \
        (__attribute__((address_space(3))) void*)(l), 16, 0, 0)

// Closed-form uniform cubic B-spline (knots -2.2 + 0.55*i, i=0..8; weights s0..s4)
__device__ __forceinline__ float spline_eval(float xn, float s0, float s1,
                                             float s2, float s3, float s4) {
    const float xc = fminf(fmaxf(xn, -1.0f), 1.0f);
    const float u = (xc + 2.2f) * (1.0f / 0.55f);
    int j = (int)u;
    j = j < 2 ? 2 : (j > 5 ? 5 : j);
    const float t = u - (float)j;
    const float omt = 1.0f - t;
    const float t2 = t * t, t3 = t2 * t;
    const float w0 = omt * omt * omt * (1.0f / 6.0f);
    const float w1 = (3.0f * t3 - 6.0f * t2 + 4.0f) * (1.0f / 6.0f);
    const float w2 = (-3.0f * t3 + 3.0f * t2 + 3.0f * t + 1.0f) * (1.0f / 6.0f);
    const float w3 = t3 * (1.0f / 6.0f);
    float so;
    if (j == 2)      so = w1 * s0 + w2 * s1 + w3 * s2;
    else if (j == 3) so = w0 * s0 + w1 * s1 + w2 * s2 + w3 * s3;
    else if (j == 4) so = w0 * s1 + w1 * s2 + w2 * s3 + w3 * s4;
    else             so = w0 * s2 + w1 * s3 + w2 * s4;
    return so;
}

// ---------------------------------------------------------------------------
// Kernel 0: blocks [0,NTOK): RMSNorm row -> xnb (bf16)
//           blocks [NTOK, NTOK+DIM): convert one W row f32 -> bf16
// ---------------------------------------------------------------------------
__global__ __launch_bounds__(256) void prep_kernel(
    const float* __restrict__ x, const float* __restrict__ nw,
    const float* __restrict__ W,
    unsigned short* __restrict__ xnb, unsigned short* __restrict__ Wb)
{
    const int bid = blockIdx.x;
    const int t = threadIdx.x;

    if (bid >= NTOK) {                    // W conversion rows
        const size_t i = (size_t)(bid - NTOK) * (DIM / 4) + t;
        const float4 v = reinterpret_cast<const float4*>(W)[i];
        ushort4 o;
        o.x = f2bf(v.x); o.y = f2bf(v.y); o.z = f2bf(v.z); o.w = f2bf(v.w);
        reinterpret_cast<ushort4*>(Wb)[i] = o;
        return;
    }

    const int lane = t & 63, wid = t >> 6;
    const float4 v = reinterpret_cast<const float4*>(x + (size_t)bid * DIM)[t];

    float ssq = v.x * v.x + v.y * v.y + v.z * v.z + v.w * v.w;
    #pragma unroll
    for (int off = 32; off; off >>= 1) ssq += __shfl_xor(ssq, off, 64);

    __shared__ float red[4];
    if (lane == 0) red[wid] = ssq;
    __syncthreads();
    const float tot = red[0] + red[1] + red[2] + red[3];
    const float r = rsqrtf(tot * (1.0f / DIM) + 1e-6f);

    const float4 nwv = reinterpret_cast<const float4*>(nw)[t];
    ushort4 xb;
    xb.x = f2bf(v.x * r * nwv.x);
    xb.y = f2bf(v.y * r * nwv.y);
    xb.z = f2bf(v.z * r * nwv.z);
    xb.w = f2bf(v.w * r * nwv.w);
    reinterpret_cast<ushort4*>(xnb + (size_t)bid * DIM)[t] = xb;
}

// ---------------------------------------------------------------------------
// Kernel 1: bf16 MFMA GEMM C[n,d] = sum_k xn[n,k] * W[d,k], fused epilogue:
//   out[n,d] = x[n,d] + (C[n,d] + spline(xn[n,d], sw[d,:])) * gamma[d]
// 64x64 tile -> 2048 blocks (8/CU by grid, 5/CU by LDS) for wave-TLP latency
// hiding (grid was the occupancy cap at 128x128). 4 waves (2x2), each wave
// 32x32 = 2x2 frags. 4-buffer LDS ring, counted vmcnt(4), raw s_barrier.
// T2 swizzle via pre-swizzled global source + swizzled ds_read offset.
// ---------------------------------------------------------------------------
__global__ __launch_bounds__(256, 5) void gemm_ep_kernel(
    const unsigned short* __restrict__ A,   // xn bf16 [NTOK][DIM]
    const unsigned short* __restrict__ B,   // W  bf16 [DIM][DIM]
    const float* __restrict__ x,
    const float* __restrict__ sw,           // [DIM][5]
    const float* __restrict__ gamma,
    float* __restrict__ out)
{
    __shared__ unsigned short SB[4 * 4096];          // 32 KB: 4 staging buffers
    float* Cs = reinterpret_cast<float*>(SB);        // epilogue alias (17.4 KB)

    const int tid = threadIdx.x;
    const int lane = tid & 63, wid = tid >> 6;

    // XCD-aware swizzle: 2048 blocks, xcd = bid&7 gets swz in [xcd*256, +256)
    // = 16 consecutive bm panels x all 16 bn  (A 2MB + W 2MB = L2-sized)
    const int bid = blockIdx.x;
    const int swz = (bid & 7) * 256 + (bid >> 3);
    const int bm = swz >> 4, bn = swz & 15;

    const int wm = wid >> 1, wn = wid & 1;

    f32x4 acc[2][2] = {};

    // staging: thread t covers row = t>>2 (0..63), 16B unit u = t&3.
    // LDS dest linear (= t*16 bytes); global source col pre-swizzled by
    // u ^ ((row>>1)&3) so ds_read-side swizzle lands conflict-free (2-way).
    const int srow = tid >> 2;
    const int scol = ((tid & 3) ^ ((tid >> 3) & 3)) * 8;
    const unsigned short* Ag = A + ((size_t)(bm * BM + srow)) * DIM + scol;
    const unsigned short* Bg = B + ((size_t)(bn * BN + srow)) * DIM + scol;
    const int oA = tid * 8;                 // shorts
    const int oB = 2048 + tid * 8;

    const int arow = wm * 32 + (lane & 15);
    const int brow = wn * 32 + (lane & 15);
    // global k-unit (lane>>4) lives at LDS unit ^ ((row>>1)&3); row bits 1-2
    // are (lane>>1)&3 for every fragment row -> per-lane constant
    const int kofs = ((lane >> 4) ^ ((lane >> 1) & 3)) * 8;

#define STAGE(bi, kt) do {                                           \
        unsigned short* sb_ = SB + (bi) * 4096;                      \
        GLOAD_LDS16(Ag + (size_t)(kt) * BK, sb_ + oA);               \
        GLOAD_LDS16(Bg + (size_t)(kt) * BK, sb_ + oB);               \
    } while (0)

#define COMP(bi) do {                                                \
        const unsigned short* sb_ = SB + (bi) * 4096;                \
        bf16x8 af[2], bfr[2];                                        \
        _Pragma("unroll")                                            \
        for (int i = 0; i < 2; ++i)                                  \
            af[i] = *reinterpret_cast<const bf16x8*>(                \
                &sb_[(arow + i * 16) * BK + kofs]);                  \
        _Pragma("unroll")                                            \
        for (int j = 0; j < 2; ++j)                                  \
            bfr[j] = *reinterpret_cast<const bf16x8*>(               \
                &sb_[2048 + (brow + j * 16) * BK + kofs]);           \
        _Pragma("unroll")                                            \
        for (int i = 0; i < 2; ++i)                                  \
            _Pragma("unroll")                                        \
            for (int j = 0; j < 2; ++j)                              \
                acc[i][j] = __builtin_amdgcn_mfma_f32_16x16x32_bf16( \
                    af[i], bfr[j], acc[i][j], 0, 0, 0);              \
    } while (0)

#define W4  asm volatile("s_waitcnt vmcnt(4)" ::: "memory")
#define W2  asm volatile("s_waitcnt vmcnt(2)" ::: "memory")
#define W0  asm volatile("s_waitcnt vmcnt(0)" ::: "memory")
#define BAR __builtin_amdgcn_s_barrier()

    STAGE(0, 0);
    STAGE(1, 1);
    #pragma unroll 1
    for (int k4 = 0; k4 < 28; k4 += 4) {
        STAGE(2, k4 + 2); W4; BAR; COMP(0);
        STAGE(3, k4 + 3); W4; BAR; COMP(1);
        STAGE(0, k4 + 4); W4; BAR; COMP(2);
        STAGE(1, k4 + 5); W4; BAR; COMP(3);
    }
    STAGE(2, 30); W4; BAR; COMP(0);
    STAGE(3, 31); W4; BAR; COMP(1);
    W2; BAR; COMP(2);
    W0; BAR; COMP(3);
    __syncthreads();

#undef STAGE
#undef COMP
#undef W4
#undef W2
#undef W0
#undef BAR

    // ---- fused epilogue (single 64x64 C-tile, padded stride 68) ----
    // write fragments
    #pragma unroll
    for (int i = 0; i < 2; ++i)
        #pragma unroll
        for (int j = 0; j < 2; ++j)
            #pragma unroll
            for (int r = 0; r < 4; ++r) {
                const int lr = wm * 32 + i * 16 + (lane >> 4) * 4 + r;
                const int cc = wn * 32 + j * 16 + (lane & 15);
                Cs[lr * 68 + cc] = acc[i][j][r];
            }
    __syncthreads();

    // stream out: thread t -> cols colg..colg+3, rows rb..rb+3
    const int colg = bn * BN + (tid & 15) * 4;
    const int rb   = (tid >> 4) * 4;
    float sf[20];
    {
        const float4* swp = reinterpret_cast<const float4*>(sw + (size_t)colg * 5);
        #pragma unroll
        for (int q = 0; q < 5; ++q) {
            const float4 w4 = swp[q];
            sf[q * 4 + 0] = w4.x; sf[q * 4 + 1] = w4.y;
            sf[q * 4 + 2] = w4.z; sf[q * 4 + 3] = w4.w;
        }
    }
    const float4 gv = *reinterpret_cast<const float4*>(gamma + colg);

    #pragma unroll
    for (int rr = 0; rr < 4; ++rr) {
        const int lr = rb + rr;
        const size_t grow = (size_t)(bm * BM + lr);
        const f32x4 cv = *reinterpret_cast<const f32x4*>(&Cs[lr * 68 + (tid & 15) * 4]);
        const float4 xv = *reinterpret_cast<const float4*>(x + grow * DIM + colg);
        const ushort4 xnv = *reinterpret_cast<const ushort4*>(A + grow * DIM + colg);
        float4 ov;
        ov.x = xv.x + (cv[0] + spline_eval(bf2f(xnv.x), sf[0],  sf[1],  sf[2],  sf[3],  sf[4]))  * gv.x;
        ov.y = xv.y + (cv[1] + spline_eval(bf2f(xnv.y), sf[5],  sf[6],  sf[7],  sf[8],  sf[9]))  * gv.y;
        ov.z = xv.z + (cv[2] + spline_eval(bf2f(xnv.z), sf[10], sf[11], sf[12], sf[13], sf[14])) * gv.z;
        ov.w = xv.w + (cv[3] + spline_eval(bf2f(xnv.w), sf[15], sf[16], sf[17], sf[18], sf[19])) * gv.w;
        *reinterpret_cast<float4*>(out + grow * DIM + colg) = ov;
    }
}

// ---------------------------------------------------------------------------
extern "C" void kernel_launch(void* const* d_in, const int* in_sizes, int n_in,
                              void* d_out, int out_size, void* d_ws, size_t ws_size,
                              hipStream_t stream) {
    const float* x     = (const float*)d_in[0];
    const float* nw    = (const float*)d_in[1];
    const float* W     = (const float*)d_in[2];
    const float* sw    = (const float*)d_in[3];
    const float* gamma = (const float*)d_in[4];
    float* out = (float*)d_out;

    unsigned short* xnb = (unsigned short*)d_ws;              // 16 MB bf16 x_norm
    unsigned short* Wb  = xnb + (size_t)NTOK * DIM;           // 2 MB bf16 W

    prep_kernel<<<dim3(NTOK + DIM), 256, 0, stream>>>(x, nw, W, xnb, Wb);
    gemm_ep_kernel<<<dim3((NTOK / BM) * (DIM / BN)), 256, 0, stream>>>(
        xnb, Wb, x, sw, gamma, out);
}